// Round 1
// 463.101 us; speedup vs baseline: 1.1104x; 1.1104x over previous
//
#include <hip/hip_runtime.h>
#include <math.h>

// ---------------------------------------------------------------------------
// SGCN forward — CSR pull aggregation fused with dense layers.
//
// R5 change: layers were VALU-issue-bound (VALUBusy 74%, MfmaUtil 0, HBM 35%).
// ~1050 wave-insts/node, dominated by fp32 fma + bf16-unpack in the dense
// phase and scalar fp32 adds in the gather. Move the datapath to packed fp16:
//   * dense uses v_dot2_f32_f16 (fp32 accumulate) -> 2 MAC/inst, no unpacks
//   * gather accumulates with v_pk_add_f16 on fp16 feature rows (128B/row,
//     halves gather L2-miss traffic); x pre-converted once by cvt_k; layer1's
//     z kept fp16 so layer2's gather also halves
//   * tanh via 1 - 2/(exp(2x)+1) (v_exp), ~6 insts vs libm ~20
// fp16 weights (2^-11) are finer than the previous bf16 (2^-8) weights, so
// absmax should DROP. CSR build (hist/scan/fill) unchanged from R4.
// ---------------------------------------------------------------------------

typedef _Float16 h2 __attribute__((ext_vector_type(2)));
typedef _Float16 h4 __attribute__((ext_vector_type(4)));

__device__ inline float fdot2f(h2 a, h2 b, float c) {
#if __has_builtin(__builtin_amdgcn_fdot2)
    return __builtin_amdgcn_fdot2(a, b, c, false);
#else
    return fmaf((float)a.x, (float)b.x, fmaf((float)a.y, (float)b.y, c));
#endif
}

__device__ inline h4 shflx4(h4 v, int m) {
    int2 i = __builtin_bit_cast(int2, v);
    i.x = __shfl_xor(i.x, m);
    i.y = __shfl_xor(i.y, m);
    return __builtin_bit_cast(h4, i);
}

__device__ inline float fast_tanh(float v) {
    float e = __expf(2.0f * v);
    return 1.0f - 2.0f / (e + 1.0f);
}

// ------------------------------- CSR build ---------------------------------

__global__ void __launch_bounds__(256) hist_k(
    const int* __restrict__ pos, const int* __restrict__ neg,
    int* __restrict__ deg, int E, int n)
{
    int e = blockIdx.x * 256 + threadIdx.x;
    if (e < E)            atomicAdd(&deg[pos[E + e]], 1);
    else if (e < 2 * E)   atomicAdd(&deg[n + neg[E + (e - E)]], 1);
}

__global__ void __launch_bounds__(256) scan1_k(
    const int* __restrict__ deg, int* __restrict__ cur,
    int* __restrict__ bsum, int n2)
{
    __shared__ int s[256];
    int tid = threadIdx.x;
    int i = blockIdx.x * 256 + tid;
    int v = (i < n2) ? deg[i] : 0;
    s[tid] = v;
    __syncthreads();
    for (int off = 1; off < 256; off <<= 1) {
        int t = (tid >= off) ? s[tid - off] : 0;
        __syncthreads();
        s[tid] += t;
        __syncthreads();
    }
    if (i < n2) cur[i] = s[tid] - v;
    if (tid == 255) bsum[blockIdx.x] = s[255];
}

__global__ void __launch_bounds__(1024) scan2_k(int* __restrict__ bsum, int nb)
{
    __shared__ int s[1024];
    int tid = threadIdx.x;
    int v = (tid < nb) ? bsum[tid] : 0;
    s[tid] = v;
    __syncthreads();
    for (int off = 1; off < 1024; off <<= 1) {
        int t = (tid >= off) ? s[tid - off] : 0;
        __syncthreads();
        s[tid] += t;
        __syncthreads();
    }
    if (tid < nb) bsum[tid] = s[tid] - v;
}

__global__ void __launch_bounds__(256) scan3_k(
    int* __restrict__ cur, const int* __restrict__ bsum, int n2)
{
    int i = blockIdx.x * 256 + threadIdx.x;
    if (i < n2) cur[i] += bsum[blockIdx.x];
}

// XCD-partitioned fill: block b serves dst-partition (b & 7); streams the
// whole edge list and fills only edges whose dst falls in its 1/8 range.
__global__ void __launch_bounds__(256) fill_k(
    const int* __restrict__ pos, const int* __restrict__ neg,
    int* __restrict__ cur, int* __restrict__ col, int E, int n,
    int blocksPerPart)
{
    int part = blockIdx.x & 7;
    int wb   = blockIdx.x >> 3;
    int n2 = 2 * n;
    int lo = (int)(((long long)n2 * part) >> 3);
    int hi = (int)(((long long)n2 * (part + 1)) >> 3);
    int stride = blocksPerPart * 256;
    for (int e = wb * 256 + (int)threadIdx.x; e < 2 * E; e += stride) {
        int node;
        if (e < E) node = pos[E + e];
        else       node = n + neg[E + (e - E)];
        if (node >= lo && node < hi) {
            int src = (e < E) ? pos[e] : neg[e - E];
            int slot = atomicAdd(&cur[node], 1);
            col[slot] = src;
        }
    }
}

// ------------------------------ x -> fp16 ----------------------------------

__global__ void __launch_bounds__(256) cvt_k(
    const float4* __restrict__ x, h4* __restrict__ xh, int n4)
{
    int i = blockIdx.x * 256 + threadIdx.x;
    if (i < n4) {
        float4 v = x[i];
        h4 o = { (_Float16)v.x, (_Float16)v.y, (_Float16)v.z, (_Float16)v.w };
        xh[i] = o;
    }
}

// ------------------------- fused pull + dense layers ------------------------
// One wave per node (grid-stride over nodes). Gather: lane = 16g+f, group g
// handles edge p0+4*it+g, f indexes an h4 (4 halves) of the 64-h row.
// Dense: lane c computes output column c (c<32 pos path, c>=32 neg path)
// with v_dot2_f32_f16 against packed-h4 weights in LDS.

__global__ void __launch_bounds__(256, 8) layer1_pull(
    const h4* __restrict__ xh,
    const int* __restrict__ cur, const int* __restrict__ col,
    const float* __restrict__ W1p, const float* __restrict__ b1p,
    const float* __restrict__ W1n, const float* __restrict__ b1n,
    _Float16* __restrict__ zh, int n)
{
    // Wq[j4*64 + c] = rows 4j4..4j4+3 (of the 128-row [a|x] matrix), column c
    // (c<32 -> W1p col c, else W1n col c-32).
    __shared__ h4 Wq[32 * 64];            // 16 KB
    __shared__ h4 vec4s[4][48];           // per-wave: a(16) | b(16) | xi(16)
    int tid = threadIdx.x;
    for (int idx = tid; idx < 32 * 64; idx += 256) {
        int j4 = idx >> 6, c = idx & 63, cw = c & 31;
        const float* Ws = (c < 32) ? W1p : W1n;
        int r = 4 * j4;
        Wq[idx] = h4{ (_Float16)Ws[r * 32 + cw],       (_Float16)Ws[(r + 1) * 32 + cw],
                      (_Float16)Ws[(r + 2) * 32 + cw], (_Float16)Ws[(r + 3) * 32 + cw] };
    }
    __syncthreads();

    int wave = tid >> 6, lane = tid & 63;
    int g = lane >> 4, f = lane & 15;
    int c = lane;
    float bb = (c < 32) ? b1p[c] : b1n[c - 32];
    int ab4 = (c < 32) ? 0 : 16;
    h4* vec = vec4s[wave];

    int stride = gridDim.x * 4;
    for (int node = blockIdx.x * 4 + wave; node < n; node += stride) {
        int p0 = node ? cur[node - 1] : 0;
        int p1 = cur[node];
        int q0 = cur[n + node - 1];
        int q1 = cur[n + node];

        h4 a = {}, b = {};
        #pragma unroll 2
        for (int it = p0 + g; it < p1; it += 4) {
            h4 t = xh[(unsigned)(col[it] * 16 + f)];
            a = a + t;
        }
        #pragma unroll 2
        for (int it = q0 + g; it < q1; it += 4) {
            h4 t = xh[(unsigned)(col[it] * 16 + f)];
            b = b + t;
        }
        a = a + shflx4(a, 16); a = a + shflx4(a, 32);
        b = b + shflx4(b, 16); b = b + shflx4(b, 32);
        _Float16 rp = (_Float16)(1.0f / (float)max(p1 - p0, 1));
        _Float16 rq = (_Float16)(1.0f / (float)max(q1 - q0, 1));
        h4 rpv = { rp, rp, rp, rp }, rqv = { rq, rq, rq, rq };
        a = a * rpv;
        b = b * rqv;
        h4 xi = xh[(unsigned)(node * 16 + f)];
        h4 sv = (g == 0) ? a : (g == 1) ? b : xi;
        if (g < 3) vec[g * 16 + f] = sv;
        __builtin_amdgcn_wave_barrier();

        float acc = bb;
        #pragma unroll
        for (int j4 = 0; j4 < 16; ++j4) {            // a-part (ap or an by half)
            h4 v = vec[ab4 + j4];
            h4 w = Wq[j4 * 64 + c];
            h2 vl = { v.x, v.y }, vh = { v.z, v.w };
            h2 wl = { w.x, w.y }, wh = { w.z, w.w };
            acc = fdot2f(vl, wl, acc);
            acc = fdot2f(vh, wh, acc);
        }
        #pragma unroll
        for (int j4 = 0; j4 < 16; ++j4) {            // x-part (shared)
            h4 v = vec[32 + j4];
            h4 w = Wq[(16 + j4) * 64 + c];
            h2 vl = { v.x, v.y }, vh = { v.z, v.w };
            h2 wl = { w.x, w.y }, wh = { w.z, w.w };
            acc = fdot2f(vl, wl, acc);
            acc = fdot2f(vh, wh, acc);
        }
        zh[(unsigned)(node * 64 + c)] = (_Float16)fast_tanh(acc);
        __builtin_amdgcn_wave_barrier();
    }
}

__global__ void __launch_bounds__(256, 8) layer2_pull(
    const h4* __restrict__ zh4,
    const int* __restrict__ cur, const int* __restrict__ col,
    const float* __restrict__ W2p, const float* __restrict__ b2p,
    const float* __restrict__ W2n, const float* __restrict__ b2n,
    float* __restrict__ out, int n)
{
    // Wq[j4*64 + c] = rows 4j4..4j4+3 of the 96-row [seg1|seg2|z] matrix.
    __shared__ h4 Wq[24 * 64];            // 12 KB
    __shared__ h4 vec4s[4][48];           // per-wave: Ap(16) | An(16) | z(16)
    int tid = threadIdx.x;
    for (int idx = tid; idx < 24 * 64; idx += 256) {
        int j4 = idx >> 6, c = idx & 63, cw = c & 31;
        const float* Ws = (c < 32) ? W2p : W2n;
        int r = 4 * j4;
        Wq[idx] = h4{ (_Float16)Ws[r * 32 + cw],       (_Float16)Ws[(r + 1) * 32 + cw],
                      (_Float16)Ws[(r + 2) * 32 + cw], (_Float16)Ws[(r + 3) * 32 + cw] };
    }
    __syncthreads();

    int wave = tid >> 6, lane = tid & 63;
    int g = lane >> 4, f = lane & 15;
    int c = lane;
    float bb = (c < 32) ? b2p[c] : b2n[c - 32];
    // vec segments (h4 units): pos half: Ap[0:32]=0..7, An[32:64]=24..31,
    // z[0:32]=32..39 ; neg half: Ap[32:64]=8..15, An[0:32]=16..23, z[32:64]=40..47
    int s1 = (c < 32) ? 0 : 8;
    int s2 = (c < 32) ? 24 : 16;
    int s3 = (c < 32) ? 32 : 40;
    h4* vec = vec4s[wave];

    int stride = gridDim.x * 4;
    for (int node = blockIdx.x * 4 + wave; node < n; node += stride) {
        int p0 = node ? cur[node - 1] : 0;
        int p1 = cur[node];
        int q0 = cur[n + node - 1];
        int q1 = cur[n + node];

        h4 a = {}, b = {};
        #pragma unroll 2
        for (int it = p0 + g; it < p1; it += 4) {
            h4 t = zh4[(unsigned)(col[it] * 16 + f)];
            a = a + t;
        }
        #pragma unroll 2
        for (int it = q0 + g; it < q1; it += 4) {
            h4 t = zh4[(unsigned)(col[it] * 16 + f)];
            b = b + t;
        }
        a = a + shflx4(a, 16); a = a + shflx4(a, 32);
        b = b + shflx4(b, 16); b = b + shflx4(b, 32);
        _Float16 rp = (_Float16)(1.0f / (float)max(p1 - p0, 1));
        _Float16 rq = (_Float16)(1.0f / (float)max(q1 - q0, 1));
        h4 rpv = { rp, rp, rp, rp }, rqv = { rq, rq, rq, rq };
        a = a * rpv;
        b = b * rqv;
        h4 zi = zh4[(unsigned)(node * 16 + f)];
        h4 sv = (g == 0) ? a : (g == 1) ? b : zi;
        if (g < 3) vec[g * 16 + f] = sv;
        __builtin_amdgcn_wave_barrier();

        float acc = bb;
        #pragma unroll
        for (int j4 = 0; j4 < 8; ++j4) {             // segment 1
            h4 v = vec[s1 + j4];
            h4 w = Wq[j4 * 64 + c];
            h2 vl = { v.x, v.y }, vh = { v.z, v.w };
            h2 wl = { w.x, w.y }, wh = { w.z, w.w };
            acc = fdot2f(vl, wl, acc);
            acc = fdot2f(vh, wh, acc);
        }
        #pragma unroll
        for (int j4 = 0; j4 < 8; ++j4) {             // segment 2
            h4 v = vec[s2 + j4];
            h4 w = Wq[(8 + j4) * 64 + c];
            h2 vl = { v.x, v.y }, vh = { v.z, v.w };
            h2 wl = { w.x, w.y }, wh = { w.z, w.w };
            acc = fdot2f(vl, wl, acc);
            acc = fdot2f(vh, wh, acc);
        }
        #pragma unroll
        for (int j4 = 0; j4 < 8; ++j4) {             // z segment
            h4 v = vec[s3 + j4];
            h4 w = Wq[(16 + j4) * 64 + c];
            h2 vl = { v.x, v.y }, vh = { v.z, v.w };
            h2 wl = { w.x, w.y }, wh = { w.z, w.w };
            acc = fdot2f(vl, wl, acc);
            acc = fdot2f(vh, wh, acc);
        }
        out[(size_t)node * 64 + c] = fast_tanh(acc);
        __builtin_amdgcn_wave_barrier();
    }
}

extern "C" void kernel_launch(void* const* d_in, const int* in_sizes, int n_in,
                              void* d_out, int out_size, void* d_ws, size_t ws_size,
                              hipStream_t stream)
{
    const float* x   = (const float*)d_in[0];
    const float* W1p = (const float*)d_in[1];
    const float* b1p = (const float*)d_in[2];
    const float* W1n = (const float*)d_in[3];
    const float* b1n = (const float*)d_in[4];
    const float* W2p = (const float*)d_in[5];
    const float* b2p = (const float*)d_in[6];
    const float* W2n = (const float*)d_in[7];
    const float* b2n = (const float*)d_in[8];
    const int*   pos = (const int*)d_in[9];
    const int*   neg = (const int*)d_in[10];

    int n = in_sizes[0] / 64;       // 100000
    int E = in_sizes[9] / 2;        // 1250000
    int n2 = 2 * n;

    // workspace: deg[2n] | cur[2n] | bsum[1024] | col[2E] | zh[n*64 fp16] | xh[n*64 fp16]
    int*      deg  = (int*)d_ws;
    int*      cur  = deg + n2;
    int*      bsum = cur + n2;
    int*      col  = bsum + 1024;
    _Float16* zh   = (_Float16*)(col + 2 * (size_t)E);
    _Float16* xh   = zh + (size_t)n * 64;

    hipMemsetAsync(deg, 0, (size_t)n2 * sizeof(int), stream);

    int eblocks = (2 * E + 255) / 256;
    int sblocks = (n2 + 255) / 256;

    hist_k <<<eblocks, 256, 0, stream>>>(pos, neg, deg, E, n);
    scan1_k<<<sblocks, 256, 0, stream>>>(deg, cur, bsum, n2);
    scan2_k<<<1, 1024, 0, stream>>>(bsum, sblocks);
    scan3_k<<<sblocks, 256, 0, stream>>>(cur, bsum, n2);

    int bpp = 128;                           // blocks per dst-partition
    fill_k <<<8 * bpp, 256, 0, stream>>>(pos, neg, cur, col, E, n, bpp);

    int n4 = n * 16;                         // h4 elements of x
    cvt_k  <<<(n4 + 255) / 256, 256, 0, stream>>>((const float4*)x, (h4*)xh, n4);

    int lblocks = 2048;   // 8 blocks/CU resident; grid-stride over nodes
    layer1_pull<<<lblocks, 256, 0, stream>>>((const h4*)xh, cur, col,
                                             W1p, b1p, W1n, b1n, zh, n);
    layer2_pull<<<lblocks, 256, 0, stream>>>((const h4*)zh, cur, col,
                                             W2p, b2p, W2n, b2n,
                                             (float*)d_out, n);
}